// Round 9
// baseline (1308.155 us; speedup 1.0000x reference)
//
#include <hip/hip_runtime.h>
#include <hip/hip_bf16.h>

#define N_CRYST 64
#define ATOMS_PER 32
#define NN 2048
#define NBRS 20
#define EE 40960
#define CC 128
#define HIDDIM 256
#define NBASIS 128
#define NLAYERS 8
#define LMAXV 6
#define KK 19
#define MAXZV 100
#define ZDIMV 256
#define FOUR_PI_F 12.566370614359172f

typedef unsigned short ushort_t;
typedef __attribute__((ext_vector_type(8))) short short8;
typedef __attribute__((ext_vector_type(4))) float floatx4;

__device__ __forceinline__ ushort_t f2us(float f) {
    union { float f; unsigned u; } x;
    x.f = f;
    unsigned r = (x.u + 0x7fffu + ((x.u >> 16) & 1u)) >> 16;
    return (ushort_t)r;
}
__device__ __forceinline__ float us2f(unsigned u) {  // low 16 bits = bf16
    return __uint_as_float(u << 16);
}

// ---------------- lattice + positions ----------------
__global__ void k_pos(const float* __restrict__ frac, const float* __restrict__ lengths,
                      const float* __restrict__ angles, const int* __restrict__ batch,
                      float* __restrict__ pos) {
    int n = blockIdx.x * blockDim.x + threadIdx.x;
    if (n >= NN) return;
    int b = batch[n];
    float la = lengths[b * 3 + 0];
    float lb = lengths[b * 3 + 1];
    float lc = lengths[b * 3 + 2];
    const float D2R = 0.017453292519943295f;
    float aa = angles[b * 3 + 0] * D2R;
    float ab = angles[b * 3 + 1] * D2R;
    float ag = angles[b * 3 + 2] * D2R;
    float ca = cosf(aa), cb = cosf(ab), cg = cosf(ag), sg = sinf(ag);
    float v3y = (ca - cb * cg) / sg;
    float v3z = sqrtf(fmaxf(1.0f - cb * cb - v3y * v3y, 1e-8f));
    float f0 = frac[n * 3 + 0];
    float f1 = frac[n * 3 + 1];
    float f2 = frac[n * 3 + 2];
    pos[n * 3 + 0] = f0 * la + f1 * (lb * cg) + f2 * (lc * cb);
    pos[n * 3 + 1] = f1 * (lb * sg) + f2 * (lc * v3y);
    pos[n * 3 + 2] = f2 * (lc * v3z);
}

// ---------------- edge geometry; Y padded to 20 (Ypad[e][19]=0) ----------------
__global__ void k_edge(const int* __restrict__ ei, const float* __restrict__ pos,
                       float* __restrict__ dist, float* __restrict__ dirn,
                       float* __restrict__ Ypad) {
    int e = blockIdx.x * blockDim.x + threadIdx.x;
    if (e >= EE) return;
    int s = ei[e], d = ei[EE + e];
    float vx = pos[s * 3 + 0] - pos[d * 3 + 0];
    float vy = pos[s * 3 + 1] - pos[d * 3 + 1];
    float vz = pos[s * 3 + 2] - pos[d * 3 + 2];
    float dd = sqrtf(vx * vx + vy * vy + vz * vz) + 1e-8f;
    float ix = vx / dd, iy = vy / dd, iz = vz / dd;
    dist[e] = dd;
    dirn[e * 3 + 0] = ix;
    dirn[e * 3 + 1] = iy;
    dirn[e * 3 + 2] = iz;

    float ct = iz;
    float rho = sqrtf(ix * ix + iy * iy) + 1e-12f;
    float cph = ix / rho, sph = iy / rho;
    float P0[LMAXV + 1];
    float P1[LMAXV + 1];
    P0[0] = 1.0f;
    P0[1] = ct;
    #pragma unroll
    for (int l = 2; l <= LMAXV; l++)
        P0[l] = ((2 * l - 1) * ct * P0[l - 1] - (l - 1) * P0[l - 2]) / (float)l;
    P1[0] = 0.0f;
    P1[1] = -rho;
    P1[2] = -3.0f * ct * rho;
    #pragma unroll
    for (int l = 3; l <= LMAXV; l++)
        P1[l] = ((2 * l - 1) * ct * P1[l - 1] - l * P1[l - 2]) / (float)(l - 1);

    float* Ye = Ypad + (size_t)e * 20;
    Ye[0] = 0.28209479177387814f;
    #pragma unroll
    for (int l = 1; l <= LMAXV; l++) {
        float K0 = sqrtf((2 * l + 1) / FOUR_PI_F);
        float K1 = sqrtf(2.0f * (2 * l + 1) / (FOUR_PI_F * l * (l + 1)));
        Ye[3 * l - 2] = K1 * P1[l] * sph;
        Ye[3 * l - 1] = K0 * P0[l];
        Ye[3 * l]     = K1 * P1[l] * cph;
    }
    Ye[19] = 0.0f;
}

// ---------------- per-tile CSR over 80 edges, grouped by src atom (layer-invariant) ----------------
__global__ void k_bcsr(const int* __restrict__ ei, int* __restrict__ bptr,
                       unsigned char* __restrict__ bedge) {
    int b = blockIdx.x;  // 512 tiles x 64 threads
    int t = threadIdx.x;
    __shared__ int cnt[32], base[32];
    if (t < 32) cnt[t] = 0;
    __syncthreads();
    int e0 = b * 80, crb = (b >> 3) * 32;
    for (int j = t; j < 80; j += 64) {
        int a = ei[e0 + j] - crb;
        atomicAdd(&cnt[a], 1);
    }
    __syncthreads();
    if (t == 0) {
        int run = 0;
        for (int a = 0; a < 32; a++) {
            base[a] = run;
            bptr[b * 33 + a] = run;
            run += cnt[a];
        }
        bptr[b * 33 + 32] = run;
    }
    __syncthreads();
    if (t < 32) cnt[t] = 0;
    __syncthreads();
    for (int j = t; j < 80; j += 64) {
        int a = ei[e0 + j] - crb;
        int slot = base[a] + atomicAdd(&cnt[a], 1);
        bedge[b * 80 + slot] = (unsigned char)j;
    }
}

// ---------------- rbf -> bf16, compact [E][128] (layer-invariant) ----------------
__global__ void k_rbfA(const float* __restrict__ dist, ushort_t* __restrict__ Abf2) {
    int idx = blockIdx.x * blockDim.x + threadIdx.x;
    if (idx >= EE * NBASIS) return;
    int e = idx >> 7, j = idx & 127;
    const float width = 8.0f / 127.0f;
    const float invw = 127.0f / 8.0f;
    float t = (dist[e] - (float)j * width) * invw;
    Abf2[idx] = f2us(expf(-0.5f * t * t));
}

// ---------------- weight transpose+cast ----------------
__global__ void k_wt(const float* __restrict__ W1, const float* __restrict__ Wd,
                     const float* __restrict__ W2,
                     ushort_t* __restrict__ WT1, ushort_t* __restrict__ WT2) {
    int idx = blockIdx.x * blockDim.x + threadIdx.x;
    const int n1 = NLAYERS * HIDDIM * 256;
    if (idx < n1) {
        int l = idx >> 16;
        int r = idx & 65535;
        int n = r >> 8, k = r & 255;
        float v = (k < 128) ? W1[((size_t)l * CC + k) * HIDDIM + n]
                            : Wd[((size_t)l * NBASIS + (k - 128)) * HIDDIM + n];
        WT1[idx] = f2us(v);
    } else {
        int j = idx - n1;
        if (j >= NLAYERS * CC * HIDDIM) return;
        int l = j >> 15;
        int r = j & 32767;
        int n = r >> 8, k = r & 255;
        WT2[j] = f2us(W2[((size_t)l * HIDDIM + k) * CC + n]);
    }
}

// ---------------- z @ zproj ----------------
__global__ void k_zc(const float* __restrict__ z, const float* __restrict__ zproj,
                     float* __restrict__ zc) {
    int idx = blockIdx.x * blockDim.x + threadIdx.x;
    if (idx >= N_CRYST * CC) return;
    int b = idx >> 7, c = idx & 127;
    float acc = 0.0f;
    for (int d = 0; d < ZDIMV; d++)
        acc += z[b * ZDIMV + d] * zproj[d * CC + c];
    zc[idx] = acc;
}

// ---------------- init x (bf16 state) ----------------
__global__ void k_xinit(const int* __restrict__ atype, const int* __restrict__ batch,
                        const float* __restrict__ emb, const float* __restrict__ zc,
                        ushort_t* __restrict__ x) {
    int idx = blockIdx.x * blockDim.x + threadIdx.x;
    if (idx >= NN * KK * CC) return;
    int n = idx / (KK * CC);
    int r = idx - n * (KK * CC);
    float v = 0.0f;
    if (r < CC) v = emb[atype[n] * CC + r] + zc[batch[n] * CC + r];
    x[idx] = f2us(v);
}

// ---------------- one layer: in-block s + GEMM1 + GEMM2 + agg per 4-node (80-edge) tile ----
// grid 512 (XCD-swizzled), block 512 (8 waves; GEMM1 strips w*32, GEMM2 w*16).
// 2 blocks/CU (LDS 33.3 KB, VGPR<=128 via launch_bounds) -> 16 waves/CU.
// LDS: As[80][40] @0 (alias Hs; Ms[80][132] spans As+Bs) ; Bs[256][40] @6400
//      (alias B2s[128][40]) ; Ys[80][20] f32 @26880.  Total 33280 B.
__global__ __launch_bounds__(512, 4) void k_layer(
        const ushort_t* __restrict__ Abf2, const ushort_t* __restrict__ WT1l,
        const ushort_t* __restrict__ WT2l, const float* __restrict__ Ypad,
        ushort_t* __restrict__ x, const int* __restrict__ bptr,
        const unsigned char* __restrict__ bedge) {
    __shared__ char smraw[33280];
    ushort_t* As  = (ushort_t*)smraw;             // [80][40]
    ushort_t* Bs  = (ushort_t*)(smraw + 6400);    // [256][40]
    ushort_t* Hs  = (ushort_t*)smraw;             // alias As
    ushort_t* B2s = (ushort_t*)(smraw + 6400);    // [128][40] alias Bs
    ushort_t* Ms  = (ushort_t*)smraw;             // [80][132]
    float* Ys     = (float*)(smraw + 26880);      // [80][20]

    int b = blockIdx.x;
    // XCD swizzle: all 8 tiles of a crystal on the same XCD (b%8)
    int cr = (b & 7) * 8 + (b >> 6);
    int sub = (b >> 3) & 7;
    int tidx = cr * 8 + sub;
    int e0 = tidx * 80;
    int crb = cr * 32;

    int t = threadIdx.x;
    int w = t >> 6, lane = t & 63;
    int quad = lane >> 4, lrow = lane & 15;
    int wn = w * 32;    // GEMM1 N strip
    int wn2 = w * 16;   // GEMM2 N strip

    // stage Y (layer-invariant region, used by s-compute and agg)
    for (int i = t; i < 80 * 20; i += 512) Ys[i] = Ypad[(size_t)e0 * 20 + i];

    int sa = t >> 4;     // s-role: atom 0..31
    int scp = t & 15;    // s-role: col-pair within 32-col chunk
    int si0 = bptr[tidx * 33 + sa];
    int si1 = bptr[tidx * 33 + sa + 1];

    floatx4 acc1[5][2];
    #pragma unroll
    for (int mi = 0; mi < 5; mi++)
        #pragma unroll
        for (int ni = 0; ni < 2; ni++)
            acc1[mi][ni] = (floatx4){0.f, 0.f, 0.f, 0.f};

    // B1 prefetch: 256x32 = 1024 vec8, 2/thread
    short8 pb[2], pc;
    int br0 = t >> 2, br1 = (512 + t) >> 2;
    int bkc = (t & 3) * 8;
    pb[0] = *(const short8*)&WT1l[(size_t)br0 * 256 + bkc];
    pb[1] = *(const short8*)&WT1l[(size_t)br1 * 256 + bkc];

    // -------- GEMM1: 8 k-chunks of 32 (0-3: s in-block; 4-7: rbf) --------
    for (int c = 0; c < 8; c++) {
        __syncthreads();
        if (c < 4) {
            int c2 = c * 32 + scp * 2;
            const ushort_t* xp = x + (size_t)(crb + sa) * (KK * CC) + c2;
            float2 xr[KK];
            #pragma unroll
            for (int k = 0; k < KK; k++) {
                unsigned u = *(const unsigned*)(xp + k * CC);
                xr[k].x = us2f(u & 0xffffu);
                xr[k].y = us2f(u >> 16);
            }
            for (int i = si0; i < si1; i++) {
                int eL = bedge[tidx * 80 + i];
                const float* yp = &Ys[eL * 20];
                float ax = 0.f, ay = 0.f;
                #pragma unroll
                for (int k = 0; k < KK; k++) {
                    float y = yp[k];
                    ax += y * xr[k].x;
                    ay += y * xr[k].y;
                }
                unsigned pk = (unsigned)f2us(ax) | (((unsigned)f2us(ay)) << 16);
                *(unsigned*)&As[eL * 40 + scp * 2] = pk;
            }
        } else if (t < 320) {  // rbf chunk: 80x32 = 320 vec8
            int r = t >> 2, kc = (t & 3) * 8;
            *(short8*)&As[r * 40 + kc] =
                *(const short8*)&Abf2[(size_t)(e0 + r) * 128 + (c - 4) * 32 + kc];
        }
        *(short8*)&Bs[br0 * 40 + bkc] = pb[0];
        *(short8*)&Bs[br1 * 40 + bkc] = pb[1];
        __syncthreads();
        if (c < 7) {
            int k0n = (c + 1) * 32;
            pb[0] = *(const short8*)&WT1l[(size_t)br0 * 256 + k0n + bkc];
            pb[1] = *(const short8*)&WT1l[(size_t)br1 * 256 + k0n + bkc];
        } else {  // prefetch B2 chunk 0: 128x32 = 512 vec8, 1/thread
            pc = *(const short8*)&WT2l[(size_t)(t >> 2) * 256 + bkc];
        }
        int kk = quad * 8;
        short8 af[5], bf[2];
        #pragma unroll
        for (int mi = 0; mi < 5; mi++)
            af[mi] = *(const short8*)&As[(mi * 16 + lrow) * 40 + kk];
        #pragma unroll
        for (int ni = 0; ni < 2; ni++)
            bf[ni] = *(const short8*)&Bs[(wn + ni * 16 + lrow) * 40 + kk];
        #pragma unroll
        for (int mi = 0; mi < 5; mi++)
            #pragma unroll
            for (int ni = 0; ni < 2; ni++)
                acc1[mi][ni] = __builtin_amdgcn_mfma_f32_16x16x32_bf16(
                    af[mi], bf[ni], acc1[mi][ni], 0, 0, 0);
    }

    // -------- GEMM2: m[80,128] = silu(h) @ WT2^T, 8 k-chunks of 32 --------
    floatx4 macc[5];
    #pragma unroll
    for (int mi = 0; mi < 5; mi++) macc[mi] = (floatx4){0.f, 0.f, 0.f, 0.f};

    #pragma unroll
    for (int nc = 0; nc < 8; nc++) {
        __syncthreads();
        if (w == nc) {  // wave nc owns h cols [nc*32, nc*32+32) in acc1
            #pragma unroll
            for (int mi = 0; mi < 5; mi++) {
                int row = mi * 16 + quad * 4;
                #pragma unroll
                for (int ni = 0; ni < 2; ni++) {
                    int col = ni * 16 + lrow;
                    #pragma unroll
                    for (int r = 0; r < 4; r++) {
                        float v = acc1[mi][ni][r];
                        v = v / (1.0f + __expf(-v));
                        Hs[(row + r) * 40 + col] = f2us(v);
                    }
                }
            }
        }
        *(short8*)&B2s[(t >> 2) * 40 + bkc] = pc;
        __syncthreads();
        if (nc < 7)
            pc = *(const short8*)&WT2l[(size_t)(t >> 2) * 256 + (nc + 1) * 32 + bkc];
        int kk = quad * 8;
        short8 af[5];
        #pragma unroll
        for (int mi = 0; mi < 5; mi++)
            af[mi] = *(const short8*)&Hs[(mi * 16 + lrow) * 40 + kk];
        short8 bf1 = *(const short8*)&B2s[(wn2 + lrow) * 40 + kk];
        #pragma unroll
        for (int mi = 0; mi < 5; mi++)
            macc[mi] = __builtin_amdgcn_mfma_f32_16x16x32_bf16(
                af[mi], bf1, macc[mi], 0, 0, 0);
    }

    __syncthreads();
    #pragma unroll
    for (int mi = 0; mi < 5; mi++) {  // macc -> Ms bf16 [80][132]
        int row = mi * 16 + quad * 4;
        int col = wn2 + lrow;
        #pragma unroll
        for (int r = 0; r < 4; r++)
            Ms[(row + r) * 132 + col] = f2us(macc[mi][r]);
    }
    __syncthreads();

    // -------- aggregation: waves 0..3 -> node w (all 20 edges), lane = col-pair ----
    if (w < 4) {
        int c2 = lane * 2;
        float2 xacc[KK];
        #pragma unroll
        for (int k = 0; k < KK; k++) xacc[k] = make_float2(0.f, 0.f);
        #pragma unroll
        for (int j = 0; j < NBRS; j++) {
            int eg = w * NBRS + j;
            unsigned mv = *(const unsigned*)&Ms[eg * 132 + c2];
            float mx = us2f(mv & 0xffffu);
            float my = us2f(mv >> 16);
            const float* yp = &Ys[eg * 20];
            #pragma unroll
            for (int kq = 0; kq < 5; kq++) {
                float4 y = *(const float4*)(yp + kq * 4);
                int k = kq * 4;
                xacc[k + 0].x += y.x * mx; xacc[k + 0].y += y.x * my;
                xacc[k + 1].x += y.y * mx; xacc[k + 1].y += y.y * my;
                xacc[k + 2].x += y.z * mx; xacc[k + 2].y += y.z * my;
                if (kq < 4) {
                    xacc[k + 3].x += y.w * mx; xacc[k + 3].y += y.w * my;
                }
            }
        }
        const float s = 1.0f / (float)NBRS;
        int ng = crb + sub * 4 + w;
        ushort_t* xp = x + (size_t)ng * (KK * CC) + c2;
        #pragma unroll
        for (int k = 0; k < KK; k++) {
            unsigned u = *(const unsigned*)(xp + k * CC);
            float ox = us2f(u & 0xffffu) + xacc[k].x * s;
            float oy = us2f(u >> 16) + xacc[k].y * s;
            unsigned pk = (unsigned)f2us(ox) | (((unsigned)f2us(oy)) << 16);
            *(unsigned*)(xp + k * CC) = pk;
        }
    }
}

// ---------------- atom logits ----------------
__global__ void k_logits(const ushort_t* __restrict__ x, const float* __restrict__ Wa,
                         const float* __restrict__ ba, float* __restrict__ out) {
    int idx = blockIdx.x * blockDim.x + threadIdx.x;
    if (idx >= NN * MAXZV) return;
    int n = idx / MAXZV, a = idx - n * MAXZV;
    float acc = ba[a];
    const ushort_t* hn = x + (size_t)n * (KK * CC);
    for (int c = 0; c < CC; c++) acc += us2f(hn[c]) * Wa[c * MAXZV + a];
    out[idx] = acc;
}

// ---------------- coord_diff ----------------
__global__ void k_coord(const int* __restrict__ ei, const ushort_t* __restrict__ x,
                        const float* __restrict__ wf, const float* __restrict__ dirn,
                        float* __restrict__ out) {
    int n = blockIdx.x;
    int t = threadIdx.x;  // 64
    __shared__ float fs[NBRS];
    __shared__ float wsh[CC];
    wsh[t] = wf[t];
    wsh[t + 64] = wf[t + 64];
    __syncthreads();
    if (t < NBRS) {
        int e = n * NBRS + t;
        int sidx = ei[e];
        const ushort_t* xs = x + (size_t)sidx * (KK * CC);
        const ushort_t* xd = x + (size_t)n * (KK * CC);
        float acc = 0.0f;
        for (int c = 0; c < CC; c++) acc += (us2f(xs[c]) - us2f(xd[c])) * wsh[c];
        fs[t] = acc;
    }
    __syncthreads();
    if (t < 3) {
        float acc = 0.0f;
        #pragma unroll
        for (int j = 0; j < NBRS; j++) acc += fs[j] * dirn[(size_t)(n * NBRS + j) * 3 + t];
        out[n * 3 + t] = acc;
    }
}

extern "C" void kernel_launch(void* const* d_in, const int* in_sizes, int n_in,
                              void* d_out, int out_size, void* d_ws, size_t ws_size,
                              hipStream_t stream) {
    (void)in_sizes; (void)n_in; (void)out_size; (void)ws_size;
    const float* z       = (const float*)d_in[0];
    const float* frac    = (const float*)d_in[1];
    const int*   atype   = (const int*)d_in[2];
    const float* lengths = (const float*)d_in[4];
    const float* angles  = (const float*)d_in[5];
    const int*   batch   = (const int*)d_in[6];
    const int*   ei      = (const int*)d_in[7];
    const float* emb     = (const float*)d_in[8];
    const float* zproj   = (const float*)d_in[9];
    const float* Wd      = (const float*)d_in[10];
    const float* W1      = (const float*)d_in[11];
    const float* W2      = (const float*)d_in[12];
    const float* Wa      = (const float*)d_in[13];
    const float* ba      = (const float*)d_in[14];
    const float* wf      = (const float*)d_in[15];
    float* out = (float*)d_out;

    float* ws = (float*)d_ws;
    float* pos  = ws; ws += NN * 3 + 4;
    float* dist = ws; ws += EE;
    float* dirn = ws; ws += EE * 3;
    float* Ypad = ws; ws += (size_t)EE * 20;
    float* zc   = ws; ws += N_CRYST * CC;
    int*   bptr = (int*)ws; ws += 512 * 33 + 4;                 // 16896 ints + pad
    unsigned char* bedge = (unsigned char*)ws; ws += (512 * 80) / 4;  // 40960 B
    ushort_t* xbf  = (ushort_t*)ws;                              // [NN][19][128] bf16
    ushort_t* Abf2 = xbf + (size_t)NN * KK * CC;                 // [E][128] rbf bf16
    ushort_t* WT1  = Abf2 + (size_t)EE * 128;                    // [8][256][256]
    ushort_t* WT2  = WT1 + (size_t)NLAYERS * 256 * 256;          // [8][128][256]

    k_pos<<<NN / 256, 256, 0, stream>>>(frac, lengths, angles, batch, pos);
    k_edge<<<EE / 256, 256, 0, stream>>>(ei, pos, dist, dirn, Ypad);
    k_bcsr<<<512, 64, 0, stream>>>(ei, bptr, bedge);
    k_rbfA<<<(EE * NBASIS) / 256, 256, 0, stream>>>(dist, Abf2);
    k_wt<<<(NLAYERS * (HIDDIM * 256 + CC * HIDDIM)) / 256, 256, 0, stream>>>(W1, Wd, W2, WT1, WT2);
    k_zc<<<(N_CRYST * CC) / 256, 256, 0, stream>>>(z, zproj, zc);
    k_xinit<<<(NN * KK * CC) / 256, 256, 0, stream>>>(atype, batch, emb, zc, xbf);

    for (int l = 0; l < NLAYERS; l++) {
        k_layer<<<512, 512, 0, stream>>>(Abf2,
                                         WT1 + (size_t)l * 65536,
                                         WT2 + (size_t)l * 32768,
                                         Ypad, xbf, bptr, bedge);
    }

    k_coord<<<NN, 64, 0, stream>>>(ei, xbf, wf, dirn, out);
    k_logits<<<(NN * MAXZV) / 256, 256, 0, stream>>>(xbf, Wa, ba, out + NN * 3);
}

// Round 10
// 1033.269 us; speedup vs baseline: 1.2660x; 1.2660x over previous
//
#include <hip/hip_runtime.h>
#include <hip/hip_bf16.h>

#define N_CRYST 64
#define ATOMS_PER 32
#define NN 2048
#define NBRS 20
#define EE 40960
#define CC 128
#define HIDDIM 256
#define NBASIS 128
#define NLAYERS 8
#define LMAXV 6
#define KK 19
#define MAXZV 100
#define ZDIMV 256
#define FOUR_PI_F 12.566370614359172f

typedef unsigned short ushort_t;
typedef __attribute__((ext_vector_type(8))) short short8;
typedef __attribute__((ext_vector_type(4))) float floatx4;

__device__ __forceinline__ ushort_t f2us(float f) {
    union { float f; unsigned u; } x;
    x.f = f;
    unsigned r = (x.u + 0x7fffu + ((x.u >> 16) & 1u)) >> 16;
    return (ushort_t)r;
}
__device__ __forceinline__ float us2f(unsigned u) {  // low 16 bits = bf16
    return __uint_as_float(u << 16);
}

// ---------------- lattice + positions ----------------
__global__ void k_pos(const float* __restrict__ frac, const float* __restrict__ lengths,
                      const float* __restrict__ angles, const int* __restrict__ batch,
                      float* __restrict__ pos) {
    int n = blockIdx.x * blockDim.x + threadIdx.x;
    if (n >= NN) return;
    int b = batch[n];
    float la = lengths[b * 3 + 0];
    float lb = lengths[b * 3 + 1];
    float lc = lengths[b * 3 + 2];
    const float D2R = 0.017453292519943295f;
    float aa = angles[b * 3 + 0] * D2R;
    float ab = angles[b * 3 + 1] * D2R;
    float ag = angles[b * 3 + 2] * D2R;
    float ca = cosf(aa), cb = cosf(ab), cg = cosf(ag), sg = sinf(ag);
    float v3y = (ca - cb * cg) / sg;
    float v3z = sqrtf(fmaxf(1.0f - cb * cb - v3y * v3y, 1e-8f));
    float f0 = frac[n * 3 + 0];
    float f1 = frac[n * 3 + 1];
    float f2 = frac[n * 3 + 2];
    pos[n * 3 + 0] = f0 * la + f1 * (lb * cg) + f2 * (lc * cb);
    pos[n * 3 + 1] = f1 * (lb * sg) + f2 * (lc * v3y);
    pos[n * 3 + 2] = f2 * (lc * v3z);
}

// ---------------- edge geometry; Y padded to 20 (Ypad[e][19]=0) ----------------
__global__ void k_edge(const int* __restrict__ ei, const float* __restrict__ pos,
                       float* __restrict__ dist, float* __restrict__ dirn,
                       float* __restrict__ Ypad) {
    int e = blockIdx.x * blockDim.x + threadIdx.x;
    if (e >= EE) return;
    int s = ei[e], d = ei[EE + e];
    float vx = pos[s * 3 + 0] - pos[d * 3 + 0];
    float vy = pos[s * 3 + 1] - pos[d * 3 + 1];
    float vz = pos[s * 3 + 2] - pos[d * 3 + 2];
    float dd = sqrtf(vx * vx + vy * vy + vz * vz) + 1e-8f;
    float ix = vx / dd, iy = vy / dd, iz = vz / dd;
    dist[e] = dd;
    dirn[e * 3 + 0] = ix;
    dirn[e * 3 + 1] = iy;
    dirn[e * 3 + 2] = iz;

    float ct = iz;
    float rho = sqrtf(ix * ix + iy * iy) + 1e-12f;
    float cph = ix / rho, sph = iy / rho;
    float P0[LMAXV + 1];
    float P1[LMAXV + 1];
    P0[0] = 1.0f;
    P0[1] = ct;
    #pragma unroll
    for (int l = 2; l <= LMAXV; l++)
        P0[l] = ((2 * l - 1) * ct * P0[l - 1] - (l - 1) * P0[l - 2]) / (float)l;
    P1[0] = 0.0f;
    P1[1] = -rho;
    P1[2] = -3.0f * ct * rho;
    #pragma unroll
    for (int l = 3; l <= LMAXV; l++)
        P1[l] = ((2 * l - 1) * ct * P1[l - 1] - l * P1[l - 2]) / (float)(l - 1);

    float* Ye = Ypad + (size_t)e * 20;
    Ye[0] = 0.28209479177387814f;
    #pragma unroll
    for (int l = 1; l <= LMAXV; l++) {
        float K0 = sqrtf((2 * l + 1) / FOUR_PI_F);
        float K1 = sqrtf(2.0f * (2 * l + 1) / (FOUR_PI_F * l * (l + 1)));
        Ye[3 * l - 2] = K1 * P1[l] * sph;
        Ye[3 * l - 1] = K0 * P0[l];
        Ye[3 * l]     = K1 * P1[l] * cph;
    }
    Ye[19] = 0.0f;
}

// ---------------- per-tile CSR over 80 edges, grouped by src atom (layer-invariant) ----------------
__global__ void k_bcsr(const int* __restrict__ ei, int* __restrict__ bptr,
                       unsigned char* __restrict__ bedge) {
    int b = blockIdx.x;  // 512 tiles x 64 threads
    int t = threadIdx.x;
    __shared__ int cnt[32], base[32];
    if (t < 32) cnt[t] = 0;
    __syncthreads();
    int e0 = b * 80, crb = (b >> 3) * 32;
    for (int j = t; j < 80; j += 64) {
        int a = ei[e0 + j] - crb;
        atomicAdd(&cnt[a], 1);
    }
    __syncthreads();
    if (t == 0) {
        int run = 0;
        for (int a = 0; a < 32; a++) {
            base[a] = run;
            bptr[b * 33 + a] = run;
            run += cnt[a];
        }
        bptr[b * 33 + 32] = run;
    }
    __syncthreads();
    if (t < 32) cnt[t] = 0;
    __syncthreads();
    for (int j = t; j < 80; j += 64) {
        int a = ei[e0 + j] - crb;
        int slot = base[a] + atomicAdd(&cnt[a], 1);
        bedge[b * 80 + slot] = (unsigned char)j;
    }
}

// ---------------- rbf -> bf16, compact [E][128] (layer-invariant) ----------------
__global__ void k_rbfA(const float* __restrict__ dist, ushort_t* __restrict__ Abf2) {
    int idx = blockIdx.x * blockDim.x + threadIdx.x;
    if (idx >= EE * NBASIS) return;
    int e = idx >> 7, j = idx & 127;
    const float width = 8.0f / 127.0f;
    const float invw = 127.0f / 8.0f;
    float t = (dist[e] - (float)j * width) * invw;
    Abf2[idx] = f2us(expf(-0.5f * t * t));
}

// ---------------- weight transpose+cast ----------------
__global__ void k_wt(const float* __restrict__ W1, const float* __restrict__ Wd,
                     const float* __restrict__ W2,
                     ushort_t* __restrict__ WT1, ushort_t* __restrict__ WT2) {
    int idx = blockIdx.x * blockDim.x + threadIdx.x;
    const int n1 = NLAYERS * HIDDIM * 256;
    if (idx < n1) {
        int l = idx >> 16;
        int r = idx & 65535;
        int n = r >> 8, k = r & 255;
        float v = (k < 128) ? W1[((size_t)l * CC + k) * HIDDIM + n]
                            : Wd[((size_t)l * NBASIS + (k - 128)) * HIDDIM + n];
        WT1[idx] = f2us(v);
    } else {
        int j = idx - n1;
        if (j >= NLAYERS * CC * HIDDIM) return;
        int l = j >> 15;
        int r = j & 32767;
        int n = r >> 8, k = r & 255;
        WT2[j] = f2us(W2[((size_t)l * HIDDIM + k) * CC + n]);
    }
}

// ---------------- z @ zproj ----------------
__global__ void k_zc(const float* __restrict__ z, const float* __restrict__ zproj,
                     float* __restrict__ zc) {
    int idx = blockIdx.x * blockDim.x + threadIdx.x;
    if (idx >= N_CRYST * CC) return;
    int b = idx >> 7, c = idx & 127;
    float acc = 0.0f;
    for (int d = 0; d < ZDIMV; d++)
        acc += z[b * ZDIMV + d] * zproj[d * CC + c];
    zc[idx] = acc;
}

// ---------------- init x (bf16 state) ----------------
__global__ void k_xinit(const int* __restrict__ atype, const int* __restrict__ batch,
                        const float* __restrict__ emb, const float* __restrict__ zc,
                        ushort_t* __restrict__ x) {
    int idx = blockIdx.x * blockDim.x + threadIdx.x;
    if (idx >= NN * KK * CC) return;
    int n = idx / (KK * CC);
    int r = idx - n * (KK * CC);
    float v = 0.0f;
    if (r < CC) v = emb[atype[n] * CC + r] + zc[batch[n] * CC + r];
    x[idx] = f2us(v);
}

// ---------------- one layer: in-block s + GEMM1 + GEMM2 + agg per 4-node (80-edge) tile ----
// grid 512 (XCD-swizzled), block 512 (8 waves). No register prefetch (spill-safe).
// GEMM1: 8 BK=32 chunks, N-strip w*32, acc1[5][2]. Then full silu(h) -> Hs[80][264].
// GEMM2: 8 BK=32 chunks from Hs, N-strip w*16, macc[5].
// LDS 58880 B: As[80][40]@0 + Bs[256][40]@6400 (GEMM1) ; Hs[80][264]@0 (after G1);
//              B2s[128][40]@42240 ; Ms[80][132]@0 (after G2) ; Ys[80][20]f32 @52480.
__global__ __launch_bounds__(512, 4) void k_layer(
        const ushort_t* __restrict__ Abf2, const ushort_t* __restrict__ WT1l,
        const ushort_t* __restrict__ WT2l, const float* __restrict__ Ypad,
        ushort_t* __restrict__ x, const int* __restrict__ bptr,
        const unsigned char* __restrict__ bedge) {
    __shared__ char smraw[58880];
    ushort_t* As  = (ushort_t*)smraw;             // [80][40]
    ushort_t* Bs  = (ushort_t*)(smraw + 6400);    // [256][40]
    ushort_t* Hs  = (ushort_t*)smraw;             // [80][264] (alias As+Bs)
    ushort_t* B2s = (ushort_t*)(smraw + 42240);   // [128][40]
    ushort_t* Ms  = (ushort_t*)smraw;             // [80][132] (alias Hs head)
    float* Ys     = (float*)(smraw + 52480);      // [80][20]

    int b = blockIdx.x;
    int cr = (b & 7) * 8 + (b >> 6);   // XCD swizzle: crystal's 8 tiles on one XCD
    int sub = (b >> 3) & 7;
    int tidx = cr * 8 + sub;
    int e0 = tidx * 80;
    int crb = cr * 32;

    int t = threadIdx.x;
    int w = t >> 6, lane = t & 63;
    int quad = lane >> 4, lrow = lane & 15;
    int wn = w * 32;    // GEMM1 N strip (8 x 32 = 256)
    int wn2 = w * 16;   // GEMM2 N strip (8 x 16 = 128)

    for (int i = t; i < 80 * 20; i += 512) Ys[i] = Ypad[(size_t)e0 * 20 + i];

    int sa = t >> 4;     // s-role: atom 0..31
    int scp = t & 15;    // s-role: col-pair within 32-col chunk
    int si0 = bptr[tidx * 33 + sa];
    int si1 = bptr[tidx * 33 + sa + 1];

    floatx4 acc1[5][2];
    #pragma unroll
    for (int mi = 0; mi < 5; mi++)
        #pragma unroll
        for (int ni = 0; ni < 2; ni++)
            acc1[mi][ni] = (floatx4){0.f, 0.f, 0.f, 0.f};

    // -------- GEMM1: 8 k-chunks of 32 (0-3: s in-block; 4-7: rbf) --------
    for (int c = 0; c < 8; c++) {
        __syncthreads();
        if (c < 4) {
            if (si1 > si0) {
                int c2 = c * 32 + scp * 2;
                const ushort_t* xp = x + (size_t)(crb + sa) * (KK * CC) + c2;
                unsigned xu[KK];
                #pragma unroll
                for (int k = 0; k < KK; k++) xu[k] = *(const unsigned*)(xp + k * CC);
                for (int i = si0; i < si1; i++) {
                    int eL = bedge[tidx * 80 + i];
                    const float* yp = &Ys[eL * 20];
                    float ax = 0.f, ay = 0.f;
                    #pragma unroll
                    for (int k = 0; k < KK; k++) {
                        float y = yp[k];
                        ax += y * us2f(xu[k] & 0xffffu);
                        ay += y * us2f(xu[k] >> 16);
                    }
                    unsigned pk = (unsigned)f2us(ax) | (((unsigned)f2us(ay)) << 16);
                    *(unsigned*)&As[eL * 40 + scp * 2] = pk;
                }
            }
        } else if (t < 320) {  // rbf chunk: 80x32 = 320 vec8
            int r = t >> 2, kc = (t & 3) * 8;
            *(short8*)&As[r * 40 + kc] =
                *(const short8*)&Abf2[(size_t)(e0 + r) * 128 + (c - 4) * 32 + kc];
        }
        {   // B1 chunk: 256x32 = 1024 vec8, 2/thread
            int r0 = t >> 2, kc = (t & 3) * 8;
            *(short8*)&Bs[r0 * 40 + kc] =
                *(const short8*)&WT1l[(size_t)r0 * 256 + c * 32 + kc];
            int r1 = r0 + 128;
            *(short8*)&Bs[r1 * 40 + kc] =
                *(const short8*)&WT1l[(size_t)r1 * 256 + c * 32 + kc];
        }
        __syncthreads();
        int kk = quad * 8;
        short8 af[5], bf[2];
        #pragma unroll
        for (int mi = 0; mi < 5; mi++)
            af[mi] = *(const short8*)&As[(mi * 16 + lrow) * 40 + kk];
        #pragma unroll
        for (int ni = 0; ni < 2; ni++)
            bf[ni] = *(const short8*)&Bs[(wn + ni * 16 + lrow) * 40 + kk];
        #pragma unroll
        for (int mi = 0; mi < 5; mi++)
            #pragma unroll
            for (int ni = 0; ni < 2; ni++)
                acc1[mi][ni] = __builtin_amdgcn_mfma_f32_16x16x32_bf16(
                    af[mi], bf[ni], acc1[mi][ni], 0, 0, 0);
    }

    __syncthreads();  // all GEMM1 LDS reads done; As/Bs region becomes Hs
    #pragma unroll
    for (int mi = 0; mi < 5; mi++) {  // silu(acc1) -> Hs[80][264], then acc1 dead
        int row = mi * 16 + quad * 4;
        #pragma unroll
        for (int ni = 0; ni < 2; ni++) {
            int col = wn + ni * 16 + lrow;
            #pragma unroll
            for (int r = 0; r < 4; r++) {
                float v = acc1[mi][ni][r];
                v = v / (1.0f + __expf(-v));
                Hs[(row + r) * 264 + col] = f2us(v);
            }
        }
    }

    // -------- GEMM2: m[80,128] = h @ WT2^T, 8 k-chunks of 32 from Hs --------
    floatx4 macc[5];
    #pragma unroll
    for (int mi = 0; mi < 5; mi++) macc[mi] = (floatx4){0.f, 0.f, 0.f, 0.f};

    #pragma unroll
    for (int nc = 0; nc < 8; nc++) {
        __syncthreads();  // Hs visible (nc=0) / prev B2s reads done
        {   // B2 chunk: 128x32 = 512 vec8, 1/thread
            int r = t >> 2, kc = (t & 3) * 8;
            *(short8*)&B2s[r * 40 + kc] =
                *(const short8*)&WT2l[(size_t)r * 256 + nc * 32 + kc];
        }
        __syncthreads();
        int kk2 = nc * 32 + quad * 8;
        short8 af2[5];
        #pragma unroll
        for (int mi = 0; mi < 5; mi++)
            af2[mi] = *(const short8*)&Hs[(mi * 16 + lrow) * 264 + kk2];
        short8 b2 = *(const short8*)&B2s[(wn2 + lrow) * 40 + quad * 8];
        #pragma unroll
        for (int mi = 0; mi < 5; mi++)
            macc[mi] = __builtin_amdgcn_mfma_f32_16x16x32_bf16(
                af2[mi], b2, macc[mi], 0, 0, 0);
    }

    __syncthreads();  // GEMM2 Hs reads done; Hs head becomes Ms
    #pragma unroll
    for (int mi = 0; mi < 5; mi++) {  // macc -> Ms bf16 [80][132]
        int row = mi * 16 + quad * 4;
        int col = wn2 + lrow;
        #pragma unroll
        for (int r = 0; r < 4; r++)
            Ms[(row + r) * 132 + col] = f2us(macc[mi][r]);
    }
    __syncthreads();

    // -------- aggregation: waves 0..3 -> node w (20 edges), lane = col-pair ----
    if (w < 4) {
        int c2 = lane * 2;
        float2 xacc[KK];
        #pragma unroll
        for (int k = 0; k < KK; k++) xacc[k] = make_float2(0.f, 0.f);
        #pragma unroll
        for (int j = 0; j < NBRS; j++) {
            int eg = w * NBRS + j;
            unsigned mv = *(const unsigned*)&Ms[eg * 132 + c2];
            float mx = us2f(mv & 0xffffu);
            float my = us2f(mv >> 16);
            const float* yp = &Ys[eg * 20];
            #pragma unroll
            for (int kq = 0; kq < 5; kq++) {
                float4 y = *(const float4*)(yp + kq * 4);
                int k = kq * 4;
                xacc[k + 0].x += y.x * mx; xacc[k + 0].y += y.x * my;
                xacc[k + 1].x += y.y * mx; xacc[k + 1].y += y.y * my;
                xacc[k + 2].x += y.z * mx; xacc[k + 2].y += y.z * my;
                if (kq < 4) {
                    xacc[k + 3].x += y.w * mx; xacc[k + 3].y += y.w * my;
                }
            }
        }
        const float s = 1.0f / (float)NBRS;
        int ng = crb + sub * 4 + w;
        ushort_t* xp = x + (size_t)ng * (KK * CC) + c2;
        #pragma unroll
        for (int k = 0; k < KK; k++) {
            unsigned u = *(const unsigned*)(xp + k * CC);
            float ox = us2f(u & 0xffffu) + xacc[k].x * s;
            float oy = us2f(u >> 16) + xacc[k].y * s;
            unsigned pk = (unsigned)f2us(ox) | (((unsigned)f2us(oy)) << 16);
            *(unsigned*)(xp + k * CC) = pk;
        }
    }
}

// ---------------- atom logits ----------------
__global__ void k_logits(const ushort_t* __restrict__ x, const float* __restrict__ Wa,
                         const float* __restrict__ ba, float* __restrict__ out) {
    int idx = blockIdx.x * blockDim.x + threadIdx.x;
    if (idx >= NN * MAXZV) return;
    int n = idx / MAXZV, a = idx - n * MAXZV;
    float acc = ba[a];
    const ushort_t* hn = x + (size_t)n * (KK * CC);
    for (int c = 0; c < CC; c++) acc += us2f(hn[c]) * Wa[c * MAXZV + a];
    out[idx] = acc;
}

// ---------------- coord_diff ----------------
__global__ void k_coord(const int* __restrict__ ei, const ushort_t* __restrict__ x,
                        const float* __restrict__ wf, const float* __restrict__ dirn,
                        float* __restrict__ out) {
    int n = blockIdx.x;
    int t = threadIdx.x;  // 64
    __shared__ float fs[NBRS];
    __shared__ float wsh[CC];
    wsh[t] = wf[t];
    wsh[t + 64] = wf[t + 64];
    __syncthreads();
    if (t < NBRS) {
        int e = n * NBRS + t;
        int sidx = ei[e];
        const ushort_t* xs = x + (size_t)sidx * (KK * CC);
        const ushort_t* xd = x + (size_t)n * (KK * CC);
        float acc = 0.0f;
        for (int c = 0; c < CC; c++) acc += (us2f(xs[c]) - us2f(xd[c])) * wsh[c];
        fs[t] = acc;
    }
    __syncthreads();
    if (t < 3) {
        float acc = 0.0f;
        #pragma unroll
        for (int j = 0; j < NBRS; j++) acc += fs[j] * dirn[(size_t)(n * NBRS + j) * 3 + t];
        out[n * 3 + t] = acc;
    }
}

extern "C" void kernel_launch(void* const* d_in, const int* in_sizes, int n_in,
                              void* d_out, int out_size, void* d_ws, size_t ws_size,
                              hipStream_t stream) {
    (void)in_sizes; (void)n_in; (void)out_size; (void)ws_size;
    const float* z       = (const float*)d_in[0];
    const float* frac    = (const float*)d_in[1];
    const int*   atype   = (const int*)d_in[2];
    const float* lengths = (const float*)d_in[4];
    const float* angles  = (const float*)d_in[5];
    const int*   batch   = (const int*)d_in[6];
    const int*   ei      = (const int*)d_in[7];
    const float* emb     = (const float*)d_in[8];
    const float* zproj   = (const float*)d_in[9];
    const float* Wd      = (const float*)d_in[10];
    const float* W1      = (const float*)d_in[11];
    const float* W2      = (const float*)d_in[12];
    const float* Wa      = (const float*)d_in[13];
    const float* ba      = (const float*)d_in[14];
    const float* wf      = (const float*)d_in[15];
    float* out = (float*)d_out;

    float* ws = (float*)d_ws;
    float* pos  = ws; ws += NN * 3 + 4;
    float* dist = ws; ws += EE;
    float* dirn = ws; ws += EE * 3;
    float* Ypad = ws; ws += (size_t)EE * 20;
    float* zc   = ws; ws += N_CRYST * CC;
    int*   bptr = (int*)ws; ws += 512 * 33 + 4;                 // 16896 ints + pad
    unsigned char* bedge = (unsigned char*)ws; ws += (512 * 80) / 4;  // 40960 B
    ushort_t* xbf  = (ushort_t*)ws;                              // [NN][19][128] bf16
    ushort_t* Abf2 = xbf + (size_t)NN * KK * CC;                 // [E][128] rbf bf16
    ushort_t* WT1  = Abf2 + (size_t)EE * 128;                    // [8][256][256]
    ushort_t* WT2  = WT1 + (size_t)NLAYERS * 256 * 256;          // [8][128][256]

    k_pos<<<NN / 256, 256, 0, stream>>>(frac, lengths, angles, batch, pos);
    k_edge<<<EE / 256, 256, 0, stream>>>(ei, pos, dist, dirn, Ypad);
    k_bcsr<<<512, 64, 0, stream>>>(ei, bptr, bedge);
    k_rbfA<<<(EE * NBASIS) / 256, 256, 0, stream>>>(dist, Abf2);
    k_wt<<<(NLAYERS * (HIDDIM * 256 + CC * HIDDIM)) / 256, 256, 0, stream>>>(W1, Wd, W2, WT1, WT2);
    k_zc<<<(N_CRYST * CC) / 256, 256, 0, stream>>>(z, zproj, zc);
    k_xinit<<<(NN * KK * CC) / 256, 256, 0, stream>>>(atype, batch, emb, zc, xbf);

    for (int l = 0; l < NLAYERS; l++) {
        k_layer<<<512, 512, 0, stream>>>(Abf2,
                                         WT1 + (size_t)l * 65536,
                                         WT2 + (size_t)l * 32768,
                                         Ypad, xbf, bptr, bedge);
    }

    k_coord<<<NN, 64, 0, stream>>>(ei, xbf, wf, dirn, out);
    k_logits<<<(NN * MAXZV) / 256, 256, 0, stream>>>(xbf, Wa, ba, out + NN * 3);
}